// Round 1
// baseline (29.897 us; speedup 1.0000x reference)
//
#include <hip/hip_runtime.h>

// DIN scorer, two-kernel split:
//  prep: for all b:  V[j,h] = W1[1152+j*36+h] + sum_i k_i W1[2304+1152*i+j*36+h]
//        emitted as bf16 B-fragments Vw[b][nt][lane][8] (h=nt*16+(lane&15), j=(lane>>4)*8+e)
//        c[b][h] = b1[h] + sum_i k_i W1[i*36+h]   (padded to 48 with zeros)
//  main: Z = Q(200x32) . V(32x36)  via mfma_f32_16x16x32_bf16
//        w[n] = b2 + sum_h sigmoid(Z[n,h]+c[h]) * W2[h]
//        out[b,j] = sum_n q[n,j] * w[n]  (fp32 butterfly)

#define BB 1024
#define NN 200
#define KK 32
#define HID 36
#define QP 40            // LDS row pitch in bf16 elems
#define PREP_BPB 4
#define PREP_BLOCKS (BB / PREP_BPB)

typedef __attribute__((ext_vector_type(8))) short bf16x8;
typedef __attribute__((ext_vector_type(4))) float f32x4;

__device__ __forceinline__ unsigned short f2bf(float x) {   // RNE f32->bf16
    unsigned int u = __float_as_uint(x);
    u = (u + 0x7fffu + ((u >> 16) & 1u)) >> 16;
    return (unsigned short)u;
}
__device__ __forceinline__ float fast_rcp(float x) {
#if __has_builtin(__builtin_amdgcn_rcpf)
    return __builtin_amdgcn_rcpf(x);
#else
    return 1.0f / x;
#endif
}

// ---------------- prep kernel: V fragments + c for all b ----------------
__global__ __launch_bounds__(256) void din_prep(
    const float* __restrict__ cad,    // [B,K]
    const float* __restrict__ W1,     // [1088*36]
    const float* __restrict__ b1,     // [36]
    unsigned short* __restrict__ Vw,  // [B][3][64][8] bf16
    float* __restrict__ Cw)           // [B][48] f32 (zero-padded)
{
    __shared__ float4 W1c[8 * 288];                        // 36864 B: 8 i-rows x 1152 f32
    __shared__ unsigned short V16s[PREP_BPB * 48 * QP];    // 15360 B

    const int tid = threadIdx.x;
    const int b0  = blockIdx.x * PREP_BPB;
    const bool two = (tid < 32);                           // owns second float4 (elems 1024..1151)

    const float4* W1q = reinterpret_cast<const float4*>(W1);

    // init accumulators with bias rows (goods-part of W1, b-independent)
    float4 a0[PREP_BPB], a1[PREP_BPB];
    {
        const float4 bias0 = W1q[288 + tid];
        float4 bias1 = make_float4(0.f, 0.f, 0.f, 0.f);
        if (two) bias1 = W1q[288 + 256 + tid];
        #pragma unroll
        for (int bl = 0; bl < PREP_BPB; ++bl) { a0[bl] = bias0; a1[bl] = bias1; }
    }

    // 4 chunks of 8 i's: stage W1 outer rows in LDS, FMA for 4 b's
    #pragma unroll 1
    for (int c = 0; c < 4; ++c) {
        #pragma unroll
        for (int ci = 0; ci < 8; ++ci) {
            W1c[ci * 288 + tid] = W1q[576 + 288 * (8 * c + ci) + tid];
            if (two) W1c[ci * 288 + 256 + tid] = W1q[576 + 288 * (8 * c + ci) + 256 + tid];
        }
        float kk[PREP_BPB][8];
        #pragma unroll
        for (int bl = 0; bl < PREP_BPB; ++bl)
            #pragma unroll
            for (int ci = 0; ci < 8; ++ci)
                kk[bl][ci] = cad[(b0 + bl) * KK + c * 8 + ci];   // uniform -> s_load
        __syncthreads();
        #pragma unroll
        for (int ci = 0; ci < 8; ++ci) {
            const float4 w0 = W1c[ci * 288 + tid];
            #pragma unroll
            for (int bl = 0; bl < PREP_BPB; ++bl) {
                a0[bl].x += kk[bl][ci] * w0.x;
                a0[bl].y += kk[bl][ci] * w0.y;
                a0[bl].z += kk[bl][ci] * w0.z;
                a0[bl].w += kk[bl][ci] * w0.w;
            }
            if (two) {
                const float4 w1 = W1c[ci * 288 + 256 + tid];
                #pragma unroll
                for (int bl = 0; bl < PREP_BPB; ++bl) {
                    a1[bl].x += kk[bl][ci] * w1.x;
                    a1[bl].y += kk[bl][ci] * w1.y;
                    a1[bl].z += kk[bl][ci] * w1.z;
                    a1[bl].w += kk[bl][ci] * w1.w;
                }
            }
        }
        __syncthreads();   // protect W1c restage
    }

    // scatter acc -> V16s[bl][h*40 + j] as bf16 (e = j*36+h, j-major linear)
    {
        int jj[4], hh[4];
        #pragma unroll
        for (int q = 0; q < 4; ++q) {
            const int e = 4 * tid + q;
            jj[q] = e / 36; hh[q] = e % 36;
        }
        #pragma unroll
        for (int bl = 0; bl < PREP_BPB; ++bl) {
            const float4 v = a0[bl];
            const float arr[4] = {v.x, v.y, v.z, v.w};
            #pragma unroll
            for (int q = 0; q < 4; ++q)
                V16s[bl * (48 * QP) + hh[q] * QP + jj[q]] = f2bf(arr[q]);
        }
        if (two) {
            int jj2[4], hh2[4];
            #pragma unroll
            for (int q = 0; q < 4; ++q) {
                const int e = 1024 + 4 * tid + q;
                jj2[q] = e / 36; hh2[q] = e % 36;
            }
            #pragma unroll
            for (int bl = 0; bl < PREP_BPB; ++bl) {
                const float4 v = a1[bl];
                const float arr[4] = {v.x, v.y, v.z, v.w};
                #pragma unroll
                for (int q = 0; q < 4; ++q)
                    V16s[bl * (48 * QP) + hh2[q] * QP + jj2[q]] = f2bf(arr[q]);
            }
        }
    }
    // zero pad rows h = 36..47 (u32 view: per-bl span 960, pad at [720,960))
    {
        unsigned int* v32 = reinterpret_cast<unsigned int*>(V16s);
        #pragma unroll
        for (int r = 0; r < 4; ++r) {
            const int p = tid + 256 * r;
            if (p < PREP_BPB * 240) {
                const int bl = p / 240, o = p % 240;
                v32[bl * 960 + 720 + o] = 0u;
            }
        }
    }
    __syncthreads();

    // coalesced fragment write: unit u (16B) = [bl][nt][lane]
    #pragma unroll
    for (int pass = 0; pass < 3; ++pass) {
        const int u  = tid + 256 * pass;              // < 768 = 4*192
        const int bl = u / 192, r = u % 192;
        const int nt = r >> 6, l = r & 63;
        const bf16x8 vv = *reinterpret_cast<const bf16x8*>(
            &V16s[bl * (48 * QP) + (nt * 16 + (l & 15)) * QP + (l >> 4) * 8]);
        *reinterpret_cast<bf16x8*>(Vw + ((size_t)b0 * 192 + u) * 8) = vv;
    }

    // c[b][48]
    if (tid < PREP_BPB * 48) {
        const int bl = tid / 48, h = tid % 48;
        float s = 0.f;
        if (h < HID) {
            s = b1[h];
            #pragma unroll
            for (int i = 0; i < KK; ++i)
                s += cad[(b0 + bl) * KK + i] * W1[i * HID + h];
        }
        Cw[(b0 + bl) * 48 + h] = s;
    }
}

// ---------------- main kernel ----------------
__global__ __launch_bounds__(256, 4) void din_main(
    const float* __restrict__ goods,  // [B,N,K]
    const float* __restrict__ W2,     // [36]
    const float* __restrict__ b2,     // [1]
    const unsigned short* __restrict__ Vw,
    const float* __restrict__ Cw,
    float* __restrict__ out)          // [B,K]
{
    __shared__ alignas(16) unsigned short Q16[208 * QP];
    __shared__ float w_s[208];
    __shared__ float red_s[4 * KK];

    const int tid  = threadIdx.x;
    const int b    = blockIdx.x;
    const int lane = tid & 63;
    const int wv   = tid >> 6;
    const int l15  = lane & 15, lk = lane >> 4;

    // ---- goods row prefetch FIRST (the HBM stream) ----
    const int nrow = (tid < NN) ? tid : (NN - 1);
    const float4* grow = reinterpret_cast<const float4*>(goods + ((size_t)b * NN + nrow) * KK);
    float4 rr[8];
    #pragma unroll
    for (int t = 0; t < 8; ++t) rr[t] = grow[t];

    // ---- V fragments / c / W2 (L2-hot, 16B coalesced) ----
    bf16x8 bfrag[3];
    #pragma unroll
    for (int nt = 0; nt < 3; ++nt)
        bfrag[nt] = *reinterpret_cast<const bf16x8*>(Vw + ((size_t)b * 192 + nt * 64 + lane) * 8);
    const float c0  = Cw[b * 48 + l15];
    const float c1  = Cw[b * 48 + 16 + l15];
    const float c2  = Cw[b * 48 + 32 + l15];
    const float w20 = W2[l15];
    const float w21 = W2[16 + l15];
    const float w22 = (l15 < HID - 32) ? W2[32 + l15] : 0.f;
    const float b2v = b2[0];

    // ---- Q -> LDS bf16 (row-major, pitch QP); rows 200..207 zero ----
    if (tid < NN) {
        uint4* qdst = reinterpret_cast<uint4*>(&Q16[tid * QP]);
        #pragma unroll
        for (int t = 0; t < 4; ++t) {
            const float4 lo = rr[2 * t], hi = rr[2 * t + 1];
            uint4 u;
            u.x = (unsigned)f2bf(lo.x) | ((unsigned)f2bf(lo.y) << 16);
            u.y = (unsigned)f2bf(lo.z) | ((unsigned)f2bf(lo.w) << 16);
            u.z = (unsigned)f2bf(hi.x) | ((unsigned)f2bf(hi.y) << 16);
            u.w = (unsigned)f2bf(hi.z) | ((unsigned)f2bf(hi.w) << 16);
            qdst[t] = u;
        }
    } else if (tid < 208) {
        uint4* qdst = reinterpret_cast<uint4*>(&Q16[tid * QP]);
        const uint4 z = make_uint4(0, 0, 0, 0);
        #pragma unroll
        for (int t = 0; t < 4; ++t) qdst[t] = z;
    }
    __syncthreads();   // Q16 ready

    // ---- MFMA phase: wave wv handles M-tiles {wv, wv+4, wv+8, wv+12} ----
    {
        #pragma unroll
        for (int t = 0; t < 4; ++t) {
            const int m = wv + 4 * t;
            if (m < 13) {
                const bf16x8 a =
                    *reinterpret_cast<const bf16x8*>(&Q16[(m * 16 + l15) * QP + lk * 8]);
                f32x4 zero = {0.f, 0.f, 0.f, 0.f};
                f32x4 d0 = __builtin_amdgcn_mfma_f32_16x16x32_bf16(a, bfrag[0], zero, 0, 0, 0);
                f32x4 d1 = __builtin_amdgcn_mfma_f32_16x16x32_bf16(a, bfrag[1], zero, 0, 0, 0);
                f32x4 d2 = __builtin_amdgcn_mfma_f32_16x16x32_bf16(a, bfrag[2], zero, 0, 0, 0);
                float part[4];
                #pragma unroll
                for (int r = 0; r < 4; ++r) {
                    float p = 0.f;
                    p += fast_rcp(1.0f + __expf(-(d0[r] + c0))) * w20;
                    p += fast_rcp(1.0f + __expf(-(d1[r] + c1))) * w21;
                    p += fast_rcp(1.0f + __expf(-(d2[r] + c2))) * w22;
                    part[r] = p;
                }
                #pragma unroll
                for (int s = 1; s <= 8; s <<= 1) {
                    #pragma unroll
                    for (int r = 0; r < 4; ++r)
                        part[r] += __shfl_xor(part[r], s, 64);
                }
                if (l15 == 0) {
                    #pragma unroll
                    for (int r = 0; r < 4; ++r)
                        w_s[m * 16 + lk * 4 + r] = b2v + part[r];
                }
            }
        }
    }
    __syncthreads();

    // ---- final: out[b,j] = sum_n q[n,j] * w[n]  (fp32 butterfly) ----
    const float w = (tid < NN) ? w_s[tid] : 0.f;

    float r[KK];
    #pragma unroll
    for (int t = 0; t < 8; ++t) {
        r[4 * t + 0] = rr[t].x; r[4 * t + 1] = rr[t].y;
        r[4 * t + 2] = rr[t].z; r[4 * t + 3] = rr[t].w;
    }
    float v[KK];
    #pragma unroll
    for (int j = 0; j < KK; ++j) v[j] = r[j] * w;

    int base = 0;
    #pragma unroll
    for (int s = 0; s < 5; ++s) {
        const int half = 16 >> s;
        const bool bit = (lane >> s) & 1;
        base += bit ? half : 0;
        #pragma unroll
        for (int t = 0; t < 16; ++t) {
            if (t < half) {
                const float keep = bit ? v[t + half] : v[t];
                const float send = bit ? v[t] : v[t + half];
                v[t] = keep + __shfl_xor(send, 1 << s, 64);
            }
        }
    }
    const float tot = v[0] + __shfl_xor(v[0], 32, 64);
    if (lane < 32) red_s[wv * KK + base] = tot;
    __syncthreads();

    if (tid < KK) {
        out[b * KK + tid] = red_s[tid] + red_s[KK + tid] +
                            red_s[2 * KK + tid] + red_s[3 * KK + tid];
    }
}

extern "C" void kernel_launch(void* const* d_in, const int* in_sizes, int n_in,
                              void* d_out, int out_size, void* d_ws, size_t ws_size,
                              hipStream_t stream) {
    const float* cad   = (const float*)d_in[0];
    const float* goods = (const float*)d_in[1];
    const float* W1    = (const float*)d_in[2];
    const float* b1    = (const float*)d_in[3];
    const float* W2    = (const float*)d_in[4];
    const float* b2    = (const float*)d_in[5];
    float* outp = (float*)d_out;

    unsigned short* Vw = (unsigned short*)d_ws;                     // 1024*192*16 B = 3 MiB
    float* Cw = (float*)((char*)d_ws + (size_t)BB * 192 * 16);      // + 192 KiB

    din_prep<<<PREP_BLOCKS, 256, 0, stream>>>(cad, W1, b1, Vw, Cw);
    din_main<<<BB, 256, 0, stream>>>(goods, W2, b2, Vw, Cw, outp);
}

// Round 2
// 23.722 us; speedup vs baseline: 1.2603x; 1.2603x over previous
//
#include <hip/hip_runtime.h>

// DIN scorer, fused single kernel:
//   V[j,h] = W1[1152+j*36+h] + sum_i k_i W1[2304+1152*i+j*36+h]   (bf16 into LDS V16)
//   c[h]   = b1[h] + sum_i k_i W1[i*36+h]
//   Z = Q(200x32) . V(32x36) via swapped-operand mfma_f32_16x16x32_bf16:
//       D = mfma(Vfrag, Qfrag) -> D[row=h, col=n]  (h-reduce = 2 shfl)
//   Q A-fragments loaded straight from global (L2-hot after rr prefetch), packed
//   with v_cvt_pk_bf16_f32 -- no Q LDS stage, no 208-row pack loop.
//   w[n] = b2 + sum_h sigmoid(Z[n,h]+c[h]) * W2[h]
//   out[b,j] = sum_n q[n,j] * w[n]   (fp32 butterfly, unchanged numerics)

#define BB 1024
#define NN 200
#define KK 32
#define HID 36
#define QP 40            // V16 row pitch in bf16 elems
#define LOG2E 1.44269504f

typedef __attribute__((ext_vector_type(8))) short bf16x8;
typedef __attribute__((ext_vector_type(4))) float f32x4;

__device__ __forceinline__ float rfl(float x) {
    return __uint_as_float(__builtin_amdgcn_readfirstlane(__float_as_uint(x)));
}
__device__ __forceinline__ unsigned short f2bf(float x) {   // RNE f32->bf16
    unsigned int u = __float_as_uint(x);
    u = (u + 0x7fffu + ((u >> 16) & 1u)) >> 16;
    return (unsigned short)u;
}
__device__ __forceinline__ unsigned int pk_bf16(float lo, float hi) { // RNE pack
    unsigned int r;
    asm("v_cvt_pk_bf16_f32 %0, %1, %2" : "=v"(r) : "v"(lo), "v"(hi));
    return r;
}
__device__ __forceinline__ float fast_rcp(float x) {
#if __has_builtin(__builtin_amdgcn_rcpf)
    return __builtin_amdgcn_rcpf(x);
#else
    return 1.0f / x;
#endif
}
__device__ __forceinline__ float fast_exp2(float x) {
#if __has_builtin(__builtin_amdgcn_exp2f)
    return __builtin_amdgcn_exp2f(x);
#else
    return exp2f(x);
#endif
}

__global__ __launch_bounds__(256, 4) void din_kernel(
    const float* __restrict__ cad,    // [B,K]
    const float* __restrict__ goods,  // [B,N,K]
    const float* __restrict__ W1,     // [1088*36]
    const float* __restrict__ b1,     // [36]
    const float* __restrict__ W2,     // [36]
    const float* __restrict__ b2,     // [1]
    float* __restrict__ out)          // [B,K]
{
    __shared__ alignas(16) unsigned short V16[48 * QP];   // [h][j] bf16, rows 36..47 zero
    __shared__ alignas(16) float c48[48];
    __shared__ alignas(16) float w248[48];
    __shared__ float w_s[208];
    __shared__ float red_s[4 * KK];

    const int tid  = threadIdx.x;
    const int b    = blockIdx.x;
    const int lane = tid & 63;
    const int wv   = tid >> 6;
    const int l15  = lane & 15, lk = lane >> 4;

    // ---- goods row prefetch FIRST (HBM stream; also fp32 data for final) ----
    const int nrow = (tid < NN) ? tid : (NN - 1);
    const float4* grow = reinterpret_cast<const float4*>(goods + ((size_t)b * NN + nrow) * KK);
    float4 rr[8];
    #pragma unroll
    for (int t = 0; t < 8; ++t) rr[t] = grow[t];

    // ---- k -> SGPRs (vectorized loads) ----
    const float4* kb4 = reinterpret_cast<const float4*>(cad + b * KK);
    float ks[KK];
    #pragma unroll
    for (int t = 0; t < 8; ++t) {
        const float4 kv = kb4[t];
        ks[4*t+0] = rfl(kv.x); ks[4*t+1] = rfl(kv.y);
        ks[4*t+2] = rfl(kv.z); ks[4*t+3] = rfl(kv.w);
    }
    const float b2v = rfl(b2[0]);

    // ---- Phase B: V fp32 accumulate, scatter bf16 directly into V16 ----
    {
        const float4* W1q = reinterpret_cast<const float4*>(W1 + 1152);
        float4 acc0 = W1q[tid];
        const bool has1 = (tid < 32);
        float4 acc1 = make_float4(0.f, 0.f, 0.f, 0.f);
        if (has1) acc1 = W1q[tid + 256];
        #pragma unroll 4
        for (int i = 0; i < KK; ++i) {
            const float ki = ks[i];
            const float4* W1o = reinterpret_cast<const float4*>(W1 + 2304 + 1152 * i);
            float4 w0 = W1o[tid];
            acc0.x += ki * w0.x; acc0.y += ki * w0.y;
            acc0.z += ki * w0.z; acc0.w += ki * w0.w;
            if (has1) {
                float4 w1v = W1o[tid + 256];
                acc1.x += ki * w1v.x; acc1.y += ki * w1v.y;
                acc1.z += ki * w1v.z; acc1.w += ki * w1v.w;
            }
        }
        {
            const float a0[4] = {acc0.x, acc0.y, acc0.z, acc0.w};
            #pragma unroll
            for (int q = 0; q < 4; ++q) {
                const int e = 4 * tid + q, j = e / 36, h = e - 36 * j;
                V16[h * QP + j] = f2bf(a0[q]);
            }
            if (has1) {
                const float a1[4] = {acc1.x, acc1.y, acc1.z, acc1.w};
                #pragma unroll
                for (int q = 0; q < 4; ++q) {
                    const int e = 1024 + 4 * tid + q, j = e / 36, h = e - 36 * j;
                    V16[h * QP + j] = f2bf(a1[q]);
                }
            }
        }
    }
    // zero pad rows h=36..47 (words 0..15 cover j=0..31; j>=32 never read)
    if (tid < 192) {
        unsigned int* v32 = reinterpret_cast<unsigned int*>(V16);
        v32[(36 + (tid >> 4)) * (QP / 2) + (tid & 15)] = 0u;
    }
    // c (padded to 48) and W2 (padded)
    if (tid < 48) {
        float accc = 0.f, w2v = 0.f;
        if (tid < HID) {
            accc = b1[tid];
            #pragma unroll
            for (int i = 0; i < KK; ++i)
                accc += ks[i] * W1[i * HID + tid];
            w2v = W2[tid];
        }
        c48[tid]  = accc;
        w248[tid] = w2v;
    }
    __syncthreads();   // V16, c48, w248 ready

    // ---- per-lane V fragments (used as MFMA A-operand) + h-constants ----
    bf16x8 bfrag[3];
    f32x4 cp[3], w2[3];
    #pragma unroll
    for (int nt = 0; nt < 3; ++nt) {
        bfrag[nt] = *reinterpret_cast<const bf16x8*>(&V16[(nt * 16 + l15) * QP + lk * 8]);
        const f32x4 cv = *reinterpret_cast<const f32x4*>(&c48[nt * 16 + lk * 4]);
        #pragma unroll
        for (int r = 0; r < 4; ++r) cp[nt][r] = -cv[r] * LOG2E;
        w2[nt] = *reinterpret_cast<const f32x4*>(&w248[nt * 16 + lk * 4]);
    }

    // ---- MFMA phase: D[row=h, col=n]; h-reduce = 12 local FMA + 2 shfl ----
    const float* gb = goods + (size_t)b * NN * KK;
    #pragma unroll
    for (int t = 0; t < 4; ++t) {
        const int m = wv + 4 * t;
        if (m < 13) {
            int row = m * 16 + l15;
            row = (row < NN) ? row : (NN - 1);      // dup rows >=200; masked later
            const float4* qp = reinterpret_cast<const float4*>(gb + row * KK + lk * 8);
            const float4 q0 = qp[0], q1 = qp[1];
            union { unsigned int u[4]; bf16x8 v; } aq;
            aq.u[0] = pk_bf16(q0.x, q0.y);
            aq.u[1] = pk_bf16(q0.z, q0.w);
            aq.u[2] = pk_bf16(q1.x, q1.y);
            aq.u[3] = pk_bf16(q1.z, q1.w);
            const f32x4 zero = {0.f, 0.f, 0.f, 0.f};
            f32x4 d0 = __builtin_amdgcn_mfma_f32_16x16x32_bf16(bfrag[0], aq.v, zero, 0, 0, 0);
            f32x4 d1 = __builtin_amdgcn_mfma_f32_16x16x32_bf16(bfrag[1], aq.v, zero, 0, 0, 0);
            f32x4 d2 = __builtin_amdgcn_mfma_f32_16x16x32_bf16(bfrag[2], aq.v, zero, 0, 0, 0);
            float p = 0.f;
            #pragma unroll
            for (int r = 0; r < 4; ++r) {
                p += fast_rcp(1.0f + fast_exp2(__builtin_fmaf(d0[r], -LOG2E, cp[0][r]))) * w2[0][r];
                p += fast_rcp(1.0f + fast_exp2(__builtin_fmaf(d1[r], -LOG2E, cp[1][r]))) * w2[1][r];
                p += fast_rcp(1.0f + fast_exp2(__builtin_fmaf(d2[r], -LOG2E, cp[2][r]))) * w2[2][r];
            }
            p += __shfl_xor(p, 16, 64);
            p += __shfl_xor(p, 32, 64);
            if (lane < 16) w_s[m * 16 + lane] = b2v + p;
        }
    }
    __syncthreads();   // w_s ready

    // ---- final: out[b,j] = sum_n q[n,j] * w[n]  (fp32 butterfly, unchanged) ----
    const float w = (tid < NN) ? w_s[tid] : 0.f;

    float r[KK];
    #pragma unroll
    for (int t = 0; t < 8; ++t) {
        r[4 * t + 0] = rr[t].x; r[4 * t + 1] = rr[t].y;
        r[4 * t + 2] = rr[t].z; r[4 * t + 3] = rr[t].w;
    }
    float v[KK];
    #pragma unroll
    for (int j = 0; j < KK; ++j) v[j] = r[j] * w;

    int base = 0;
    #pragma unroll
    for (int s = 0; s < 5; ++s) {
        const int half = 16 >> s;
        const bool bit = (lane >> s) & 1;
        base += bit ? half : 0;
        #pragma unroll
        for (int t = 0; t < 16; ++t) {
            if (t < half) {
                const float keep = bit ? v[t + half] : v[t];
                const float send = bit ? v[t] : v[t + half];
                v[t] = keep + __shfl_xor(send, 1 << s, 64);
            }
        }
    }
    const float tot = v[0] + __shfl_xor(v[0], 32, 64);
    if (lane < 32) red_s[wv * KK + base] = tot;
    __syncthreads();

    if (tid < KK) {
        out[b * KK + tid] = red_s[tid] + red_s[KK + tid] +
                            red_s[2 * KK + tid] + red_s[3 * KK + tid];
    }
}

extern "C" void kernel_launch(void* const* d_in, const int* in_sizes, int n_in,
                              void* d_out, int out_size, void* d_ws, size_t ws_size,
                              hipStream_t stream) {
    const float* cad   = (const float*)d_in[0];
    const float* goods = (const float*)d_in[1];
    const float* W1    = (const float*)d_in[2];
    const float* b1    = (const float*)d_in[3];
    const float* W2    = (const float*)d_in[4];
    const float* b2    = (const float*)d_in[5];
    float* outp = (float*)d_out;

    din_kernel<<<BB, 256, 0, stream>>>(cad, goods, W1, b1, W2, b2, outp);
}